// Round 10
// baseline (416.768 us; speedup 1.0000x reference)
//
#include <hip/hip_runtime.h>
#include <hip/hip_bf16.h>

#define N_ROWS 8192
#define DIM 512
#define C_CLSN 1000
#define C_PAD 1024
#define LOW_THRE (1.0f / 1000.0f)
#define LDK 40    // bf16 LDS leading dim (elems)
#define LDF8 72   // fp8 LDS leading dim (bytes): %8==0 for b64 reads, bank-conflict-free

typedef __bf16 bf16x8 __attribute__((ext_vector_type(8)));
typedef float floatx4 __attribute__((ext_vector_type(4)));
typedef unsigned long long ull;
typedef ull ull2 __attribute__((ext_vector_type(2)));

// ---------------- KZP: detect conf storage + stable partition (fused) --------
__global__ __launch_bounds__(1024) void kzp_v10(const int* __restrict__ conf,
                                                int* __restrict__ perm,
                                                int* __restrict__ counters) {
  int tid = threadIdx.x;
  __shared__ int sc[1024];
  __shared__ int sbad, sodd1, seven1, smode;
  if (tid == 0) { sbad = 0; sodd1 = 0; seven1 = 0; }
  __syncthreads();
  for (int i = tid; i < 2048; i += 1024) {
    int v = conf[i];
    if (v != 0 && v != 1) atomicOr(&sbad, 1);
    if (v == 1) { if (i & 1) atomicAdd(&sodd1, 1); else atomicAdd(&seven1, 1); }
  }
  __syncthreads();
  if (tid == 0) {
    int mode = 0;                                // int32 0/1
    if (sbad) mode = 1;                          // packed uint8 bools
    else if (seven1 > 0 && sodd1 == 0) mode = 2; // int64 0/1
    smode = mode;
  }
  __syncthreads();
  int mode = smode;
  int r0 = tid * 8;
  int f[8]; int cnt = 0;
  #pragma unroll
  for (int k = 0; k < 8; ++k) {
    int r = r0 + k;
    bool c;
    if (mode == 1)      c = ((const unsigned char*)conf)[r] != 0;
    else if (mode == 2) c = ((const long long*)conf)[r] != 0;
    else                c = conf[r] != 0;
    f[k] = c ? 1 : 0; cnt += f[k];
  }
  sc[tid] = cnt;
  __syncthreads();
  for (int off = 1; off < 1024; off <<= 1) {    // Hillis-Steele inclusive scan
    int v = (tid >= off) ? sc[tid - off] : 0;
    __syncthreads();
    sc[tid] += v;
    __syncthreads();
  }
  int incl = sc[tid];
  int excl = incl - cnt;
  int total = sc[1023];
  if (tid == 0) counters[3] = total;
  int cpos = excl;
  int npos = total + (r0 - excl);
  #pragma unroll
  for (int k = 0; k < 8; ++k) {
    if (f[k]) perm[cpos++] = r0 + k;
    else      perm[npos++] = r0 + k;
  }
}

// ---------------- KDABC: [0,2048) prob+featnorm | [2048,2176) proxy proj -----
__global__ __launch_bounds__(256) void kdabc_v10(const float* __restrict__ prob,
                                                 const float* __restrict__ feature,
                                                 const float* __restrict__ raw,
                                                 const float* __restrict__ cP,
                                                 const int* __restrict__ perm,
                                                 ull* __restrict__ bits,
                                                 int* __restrict__ top1a,
                                                 __bf16* __restrict__ featBF,
                                                 unsigned char* __restrict__ featF8,
                                                 __bf16* __restrict__ proxyBF,
                                                 int* counters) {
  __shared__ float sraw[8 * DIM];  // 16 KB (kbc part only)
  __shared__ float red[8 * 256];   // 8 KB
  if (blockIdx.x >= 2048) {
    // ---- KBC: proxy projection + normalize -> bf16, pad rows zeroed ----
    int tid = threadIdx.x;
    int c0 = (blockIdx.x - 2048) * 8;
    int d0 = tid, d1 = tid + 256;
    if (c0 >= C_CLSN) {
      #pragma unroll
      for (int cc = 0; cc < 8; ++cc) {
        proxyBF[(size_t)(c0 + cc) * DIM + d0] = (__bf16)0.f;
        proxyBF[(size_t)(c0 + cc) * DIM + d1] = (__bf16)0.f;
      }
      return;
    }
    for (int idx = tid; idx < 8 * DIM; idx += 256)
      sraw[idx] = raw[(size_t)c0 * DIM + idx];
    __syncthreads();
    float acc0[8], acc1[8];
    #pragma unroll
    for (int cc = 0; cc < 8; ++cc) { acc0[cc] = 0.f; acc1[cc] = 0.f; }
    for (int k = 0; k < DIM; k += 4) {
      float4 w0 = *(const float4*)&cP[(size_t)d0 * DIM + k];
      float4 w1 = *(const float4*)&cP[(size_t)d1 * DIM + k];
      #pragma unroll
      for (int cc = 0; cc < 8; ++cc) {
        const float* sr = &sraw[cc * DIM + k];
        acc0[cc] += sr[0]*w0.x + sr[1]*w0.y + sr[2]*w0.z + sr[3]*w0.w;
        acc1[cc] += sr[0]*w1.x + sr[1]*w1.y + sr[2]*w1.z + sr[3]*w1.w;
      }
    }
    #pragma unroll
    for (int cc = 0; cc < 8; ++cc)
      red[cc * 256 + tid] = acc0[cc]*acc0[cc] + acc1[cc]*acc1[cc];
    __syncthreads();
    for (int s = 128; s > 0; s >>= 1) {
      if (tid < s)
        #pragma unroll
        for (int cc = 0; cc < 8; ++cc)
          red[cc * 256 + tid] += red[cc * 256 + tid + s];
      __syncthreads();
    }
    #pragma unroll
    for (int cc = 0; cc < 8; ++cc) {
      float scl = 1.0f / fmaxf(sqrtf(red[cc * 256]), 1e-12f);
      proxyBF[(size_t)(c0 + cc) * DIM + d0] = (__bf16)(acc0[cc] * scl);
      proxyBF[(size_t)(c0 + cc) * DIM + d1] = (__bf16)(acc1[cc] * scl);
    }
    return;
  }
  // ---- KDA: prob scan + feature normalize -> bf16 + fp8 ----
  int wv = threadIdx.x >> 6, lane = threadIdx.x & 63;
  int p = blockIdx.x * 4 + wv;
  int orig = perm[p];
  bool is_conf = p < counters[3];
  const float* pr = prob + (size_t)orig * C_CLSN;
  float bv = -1e30f; int bidx = 0x7fffffff;
  int cnt = 0;
  ull myword = 0ULL;
  #pragma unroll
  for (int pass = 0; pass < 16; ++pass) {
    int c = pass * 64 + lane;
    float pv = (c < C_CLSN) ? pr[c] : -1.0f;
    if (pv > bv) { bv = pv; bidx = c; }
    ull m = __ballot((c < C_CLSN) && (pv > LOW_THRE));
    cnt += (int)__popcll(m);
    if (lane == pass) myword = m;
  }
  #pragma unroll
  for (int m = 1; m < 64; m <<= 1) {           // wave argmax, first-occurrence
    float ov = __shfl_xor(bv, m); int oi = __shfl_xor(bidx, m);
    if (ov > bv || (ov == bv && oi < bidx)) { bv = ov; bidx = oi; }
  }
  int top1 = bidx;
  if (is_conf && lane < 16)
    myword = (lane == (top1 >> 6)) ? (1ULL << (top1 & 63)) : 0ULL;
  if (lane < 16) bits[(size_t)p * 16 + lane] = myword;
  if (lane == 0) {
    top1a[p] = top1;
    if (!is_conf) {
      atomicAdd(&counters[0], cnt);            // sc_count
      atomicAdd(&counters[1], 1);              // denom
    }
  }
  const float* fr = feature + (size_t)orig * DIM;
  int c0 = lane * 8;
  float4 v0 = *(const float4*)(fr + c0);
  float4 v1 = *(const float4*)(fr + c0 + 4);
  float ss = v0.x*v0.x + v0.y*v0.y + v0.z*v0.z + v0.w*v0.w
           + v1.x*v1.x + v1.y*v1.y + v1.z*v1.z + v1.w*v1.w;
  #pragma unroll
  for (int m = 1; m < 64; m <<= 1) ss += __shfl_xor(ss, m);
  float scl = 1.0f / fmaxf(sqrtf(ss), 1e-12f);
  float x0 = v0.x*scl, x1 = v0.y*scl, x2 = v0.z*scl, x3 = v0.w*scl;
  float x4 = v1.x*scl, x5 = v1.y*scl, x6 = v1.z*scl, x7 = v1.w*scl;
  bf16x8 bvx;
  bvx[0] = (__bf16)x0; bvx[1] = (__bf16)x1; bvx[2] = (__bf16)x2; bvx[3] = (__bf16)x3;
  bvx[4] = (__bf16)x4; bvx[5] = (__bf16)x5; bvx[6] = (__bf16)x6; bvx[7] = (__bf16)x7;
  *(bf16x8*)(featBF + (size_t)p * DIM + c0) = bvx;
  int lo = __builtin_amdgcn_cvt_pk_fp8_f32(x0, x1, 0, false);
  lo = __builtin_amdgcn_cvt_pk_fp8_f32(x2, x3, lo, true);
  int hi = __builtin_amdgcn_cvt_pk_fp8_f32(x4, x5, 0, false);
  hi = __builtin_amdgcn_cvt_pk_fp8_f32(x6, x7, hi, true);
  int2 pk; pk.x = lo; pk.y = hi;
  *(int2*)(featF8 + (size_t)p * DIM + c0) = pk;
}

// ---------------- KEGG: grid-partitioned fusion ------------------------------
// blocks [0,512): kg  P=feat@proxy^T (bf16) + pos-pair epilogue
// blocks [512,2592): ke  fp8 sim GEMM + mask + sum(exp), register-prefetch K-loop
__global__ __launch_bounds__(512) void kegg_v10(const __bf16* __restrict__ featBF,
                                                const __bf16* __restrict__ proxyBF,
                                                const unsigned char* __restrict__ featF8,
                                                const float* __restrict__ prob,
                                                const ull* __restrict__ bits,
                                                const int* __restrict__ perm,
                                                const int* __restrict__ top1a,
                                                const int* __restrict__ counters_ro,
                                                float* __restrict__ scsim,
                                                float* __restrict__ possim,
                                                float* __restrict__ S) {
  __shared__ __align__(16) char smem[35840];
  int tid = threadIdx.x;
  int wv = tid >> 6, lane = tid & 63;
  int wi = wv >> 2, wj = wv & 3;            // 2x4 wave grid: 64 rows x 32 cols
  int lr = lane >> 4, lc = lane & 15;

  floatx4 acc[4][2];
  floatx4 zero = {0.f, 0.f, 0.f, 0.f};
  #pragma unroll
  for (int ti = 0; ti < 4; ++ti)
    #pragma unroll
    for (int tj = 0; tj < 2; ++tj) acc[ti][tj] = zero;

  if (blockIdx.x < 512) {
    // ================= KG path (bf16) =================
    __bf16* As = (__bf16*)smem;                  // 10240 B
    __bf16* Bs = (__bf16*)(smem + 10240);        // 10240 B
    int* pO  = (int*)(smem + 20480);             // 512 B
    int* t1r = (int*)(smem + 20992);             // 512 B
    int bi = blockIdx.x >> 3;     // 64 row-tiles
    int bj = blockIdx.x & 7;      // 8 class-tiles
    if (tid < 128) { pO[tid] = perm[bi * 128 + tid]; t1r[tid] = top1a[bi * 128 + tid]; }
    const __bf16* Abase = featBF + (size_t)bi * 128 * DIM;
    const __bf16* Bbase = proxyBF + (size_t)bj * 128 * DIM;
    for (int kt = 0; kt < DIM; kt += 32) {
      __syncthreads();
      {
        int rw = tid >> 2, cc = (tid & 3) * 8;
        *(bf16x8*)&As[rw * LDK + cc] = *(const bf16x8*)&Abase[(size_t)rw * DIM + kt + cc];
        *(bf16x8*)&Bs[rw * LDK + cc] = *(const bf16x8*)&Bbase[(size_t)rw * DIM + kt + cc];
      }
      __syncthreads();
      bf16x8 afr[4], bfr[2];
      #pragma unroll
      for (int ti = 0; ti < 4; ++ti)
        afr[ti] = *(bf16x8*)&As[(wi * 64 + ti * 16 + lc) * LDK + lr * 8];
      #pragma unroll
      for (int tj = 0; tj < 2; ++tj)
        bfr[tj] = *(bf16x8*)&Bs[(wj * 32 + tj * 16 + lc) * LDK + lr * 8];
      #pragma unroll
      for (int ti = 0; ti < 4; ++ti)
        #pragma unroll
        for (int tj = 0; tj < 2; ++tj)
          acc[ti][tj] = __builtin_amdgcn_mfma_f32_16x16x32_bf16(afr[ti], bfr[tj], acc[ti][tj], 0, 0, 0);
    }
    __syncthreads();
    #pragma unroll
    for (int ti = 0; ti < 4; ++ti) {
      int ibase = wi * 64 + ti * 16 + lr * 4;   // C/D: row=(lane>>4)*4+reg, col=lane&15
      float rs[4] = {0.f, 0.f, 0.f, 0.f};
      #pragma unroll
      for (int rr = 0; rr < 4; ++rr) {
        int il = ibase + rr;
        int orig = pO[il];
        int t1 = t1r[il];
        const float* prow = prob + (size_t)orig * C_CLSN;
        #pragma unroll
        for (int tj = 0; tj < 2; ++tj) {
          int c = bj * 128 + wj * 32 + tj * 16 + lc;
          float P = acc[ti][tj][rr];
          float pv = (c < C_CLSN) ? prow[c] : 0.f;
          if (pv > LOW_THRE) rs[rr] += pv * P;
          if (c == t1) possim[bi * 128 + il] = P;   // single writer grid-wide
        }
      }
      #pragma unroll
      for (int m = 1; m < 16; m <<= 1)
        #pragma unroll
        for (int rr = 0; rr < 4; ++rr) rs[rr] += __shfl_xor(rs[rr], m);
      if (lc == 0) {
        #pragma unroll
        for (int rr = 0; rr < 4; ++rr)
          atomicAdd(&scsim[bi * 128 + ibase + rr], rs[rr]);
      }
    }
    return;
  }

  // ================= KE path (fp8) =================
  unsigned char* As = (unsigned char*)smem;           // 9216 B
  unsigned char* Bs = (unsigned char*)(smem + 9216);  // 9216 B
  ull* bsJ = (ull*)smem;                              // 16384 B, aliases As+Bs post-loop
  ull* bsI = (ull*)(smem + 18432);                    // 16384 B (dedicated)
  int* t1I = (int*)(smem + 34816);                    // 512 B
  int* t1J = (int*)(smem + 35328);                    // 512 B

  // LCG swizzle interleaves heavy (mode-3) and light tiles
  int b = (int)(((long long)(blockIdx.x - 512) * 997) % 2080);
  int bi = 0, rem = b;
  while (rem >= 64 - bi) { rem -= 64 - bi; bi++; }
  int bj = bi + rem;

  int nconf = counters_ro[3];
  bool allcI = (bi * 128 + 128) <= nconf;
  bool allcJ = (bj * 128 + 128) <= nconf;
  int mode = allcJ ? 0 : (allcI ? 1 : 3);   // bi<=bj + conf-first => allcJ -> allcI

  if (tid < 128)      t1I[tid]       = top1a[bi * 128 + tid];
  else if (tid < 256) t1J[tid - 128] = top1a[bj * 128 + tid - 128];
  if (mode == 3) {    // bsI dedicated: stage before K-loop
    #pragma unroll
    for (int e = 0; e < 4; ++e) {
      int flat = tid + e * 512;
      int row = flat & 127, w = flat >> 7;
      bsI[w * 128 + row] = bits[(size_t)(bi * 128 + row) * 16 + w];
    }
  }

  int rw = tid >> 2, cc = (tid & 3) * 16;
  const unsigned char* Aptr = featF8 + (size_t)(bi * 128 + rw) * DIM + cc;
  const unsigned char* Bptr = featF8 + (size_t)(bj * 128 + rw) * DIM + cc;
  int4 pa = *(const int4*)Aptr;             // prefetch kt=0
  int4 pb = *(const int4*)Bptr;

  for (int kt = 0; kt < DIM; kt += 64) {    // 8 iterations
    __syncthreads();
    *(int4*)&As[rw * LDF8 + cc] = pa;
    *(int4*)&Bs[rw * LDF8 + cc] = pb;
    __syncthreads();
    if (kt + 64 < DIM) {                    // prefetch next iter during MFMA
      pa = *(const int4*)(Aptr + kt + 64);
      pb = *(const int4*)(Bptr + kt + 64);
    }
    // fp8 16x16x32 frag: row = lane&15, k = (lane>>4)*8 + byte
    #pragma unroll
    for (int ks = 0; ks < 2; ++ks) {
      long a_[4], b_[2];
      #pragma unroll
      for (int ti = 0; ti < 4; ++ti)
        a_[ti] = *(const long*)&As[(wi * 64 + ti * 16 + lc) * LDF8 + ks * 32 + lr * 8];
      #pragma unroll
      for (int tj = 0; tj < 2; ++tj)
        b_[tj] = *(const long*)&Bs[(wj * 32 + tj * 16 + lc) * LDF8 + ks * 32 + lr * 8];
      #pragma unroll
      for (int ti = 0; ti < 4; ++ti)
        #pragma unroll
        for (int tj = 0; tj < 2; ++tj)
          acc[ti][tj] = __builtin_amdgcn_mfma_f32_16x16x32_fp8_fp8(a_[ti], b_[tj], acc[ti][tj], 0, 0, 0);
    }
  }
  __syncthreads();              // all waves done reading As/Bs
  if (mode != 0) {              // stage bsJ into the aliased region
    #pragma unroll
    for (int e = 0; e < 4; ++e) {
      int flat = tid + e * 512;
      int row = flat & 127, w = flat >> 7;
      bsJ[w * 128 + row] = bits[(size_t)(bj * 128 + row) * 16 + w];
    }
  }
  __syncthreads();

  int tJv[2];
  #pragma unroll
  for (int tj = 0; tj < 2; ++tj) tJv[tj] = t1J[wj * 32 + tj * 16 + lc];

  float cs[2] = {0.f, 0.f};     // mirror column partial sums
  #pragma unroll
  for (int ti = 0; ti < 4; ++ti) {
    int ibase = wi * 64 + ti * 16 + lr * 4;
    unsigned inter[8];
    if (mode == 0) {            // conf x conf: intersect <=> same top1
      #pragma unroll
      for (int rr = 0; rr < 4; ++rr) {
        int tI = t1I[ibase + rr];
        #pragma unroll
        for (int tj = 0; tj < 2; ++tj) inter[rr * 2 + tj] = (tI == tJv[tj]);
      }
    } else if (mode == 1) {     // conf-I: probe J's bitset with top1_i
      #pragma unroll
      for (int rr = 0; rr < 4; ++rr) {
        int tI = t1I[ibase + rr];
        int w = tI >> 6, bb = tI & 63;
        #pragma unroll
        for (int tj = 0; tj < 2; ++tj) {
          ull word = bsJ[w * 128 + wj * 32 + tj * 16 + lc];
          inter[rr * 2 + tj] = (unsigned)((word >> bb) & 1ULL);
        }
      }
    } else {                    // general: full 1000-bit AND
      #pragma unroll
      for (int q = 0; q < 8; ++q) inter[q] = 0u;
      #pragma unroll
      for (int w = 0; w < 16; ++w) {
        ull2 a01 = *(const ull2*)&bsI[w * 128 + ibase];
        ull2 a23 = *(const ull2*)&bsI[w * 128 + ibase + 2];
        ull aw[4] = {a01[0], a01[1], a23[0], a23[1]};
        ull bw[2];
        #pragma unroll
        for (int tj = 0; tj < 2; ++tj) bw[tj] = bsJ[w * 128 + wj * 32 + tj * 16 + lc];
        #pragma unroll
        for (int rr = 0; rr < 4; ++rr)
          #pragma unroll
          for (int tj = 0; tj < 2; ++tj) {
            ull t = aw[rr] & bw[tj];
            inter[rr * 2 + tj] |= (unsigned)(t | (t >> 32));
          }
      }
    }
    float rs[4] = {0.f, 0.f, 0.f, 0.f};
    #pragma unroll
    for (int rr = 0; rr < 4; ++rr)
      #pragma unroll
      for (int tj = 0; tj < 2; ++tj) {
        float sim = acc[ti][tj][rr];
        sim = fminf(sim, 1.0f);   // unit rows: math no-op
        float e_ = ((inter[rr * 2 + tj] == 0u) && (sim >= 1e-6f)) ? __expf(sim) : 0.f;
        rs[rr] += e_;
        cs[tj] += e_;
      }
    #pragma unroll
    for (int m = 1; m < 16; m <<= 1)
      #pragma unroll
      for (int rr = 0; rr < 4; ++rr) rs[rr] += __shfl_xor(rs[rr], m);
    if (lc == 0) {
      #pragma unroll
      for (int rr = 0; rr < 4; ++rr)
        atomicAdd(&S[(size_t)bi * 128 + ibase + rr], rs[rr]);
    }
  }
  if (bi != bj) {   // mirror: (j,i) identical by symmetry -> column sums
    #pragma unroll
    for (int tj = 0; tj < 2; ++tj) {
      cs[tj] += __shfl_xor(cs[tj], 16);   // reduce over lr
      cs[tj] += __shfl_xor(cs[tj], 32);
    }
    if (lr == 0) {
      #pragma unroll
      for (int tj = 0; tj < 2; ++tj)
        atomicAdd(&S[(size_t)bj * 128 + wj * 32 + tj * 16 + lc], cs[tj]);
    }
  }
}

// ---------------- KF: final reduction — fp32 out -----------------------------
__global__ __launch_bounds__(1024) void kf_final_v10(const float* __restrict__ possim,
                                                     const float* __restrict__ scsim,
                                                     const float* __restrict__ S,
                                                     const int* __restrict__ counters,
                                                     float* __restrict__ out) {
  __shared__ float red[1024];
  int tid = threadIdx.x;
  int nconf = counters[3];
  float local = 0.f;
  for (int i = tid; i < N_ROWS; i += 1024) {
    float p = (i < nconf) ? possim[i] : scsim[i];
    p = fminf(fmaxf(p, -1.1f), 1.1f);      // |pos|<=1 math bound (safety)
    float s = fmaxf(S[i], 0.0f);
    local += logf(expf(p) + s) - p;        // -logp[:,0]
  }
  red[tid] = local;
  __syncthreads();
  for (int s = 512; s > 0; s >>= 1) {
    if (tid < s) red[tid] += red[tid + s];
    __syncthreads();
  }
  if (tid == 0) {
    float loss = red[0] / (float)N_ROWS;
    int scc = counters[0], dn = counters[1];
    float scn = (dn > 0) ? ((float)scc / (float)(dn > 1 ? dn : 1)) : 0.f;
    out[0] = loss;
    out[1] = scn;
  }
}

extern "C" void kernel_launch(void* const* d_in, const int* in_sizes, int n_in,
                              void* d_out, int out_size, void* d_ws, size_t ws_size,
                              hipStream_t stream) {
  const float* feature   = (const float*)d_in[0];
  const float* proxy_raw = (const float*)d_in[1];
  const float* cP        = (const float*)d_in[2];
  const float* prob      = (const float*)d_in[3];
  const int*   conf      = (const int*)d_in[4];
  float* out = (float*)d_out;

  size_t need = (size_t)N_ROWS * DIM * 2      // featBF    8 MB
              + (size_t)N_ROWS * DIM          // featF8    4 MB
              + (size_t)C_PAD * DIM * 2       // proxyBF   1 MB
              + (size_t)N_ROWS * 16 * 8       // bits      1 MB
              + (size_t)N_ROWS * 4            // possim
              + (size_t)N_ROWS * 4            // S
              + (size_t)N_ROWS * 4            // scsim
              + 256                           // counters
              + (size_t)N_ROWS * 4            // perm
              + (size_t)N_ROWS * 4;           // top1a
  if (ws_size < need) return;

  char* ws = (char*)d_ws;
  __bf16* featBF  = (__bf16*)ws;              ws += (size_t)N_ROWS * DIM * 2;
  unsigned char* featF8 = (unsigned char*)ws; ws += (size_t)N_ROWS * DIM;
  __bf16* proxyBF = (__bf16*)ws;              ws += (size_t)C_PAD * DIM * 2;
  ull* bits       = (ull*)ws;                 ws += (size_t)N_ROWS * 16 * 8;
  float* possim   = (float*)ws;               ws += (size_t)N_ROWS * 4;
  float* S        = (float*)ws;               ws += (size_t)N_ROWS * 4;  // S,scsim,counters contiguous
  float* scsim    = (float*)ws;               ws += (size_t)N_ROWS * 4;
  int* counters   = (int*)ws;                 ws += 256;  // [0]=sc_count [1]=denom [3]=nconf
  int* perm       = (int*)ws;                 ws += (size_t)N_ROWS * 4;
  int* top1a      = (int*)ws;                 ws += (size_t)N_ROWS * 4;

  hipMemsetAsync(S, 0, (size_t)N_ROWS * 8 + 256, stream);  // zero S + scsim + counters
  kzp_v10<<<1, 1024, 0, stream>>>(conf, perm, counters);
  kdabc_v10<<<2176, 256, 0, stream>>>(prob, feature, proxy_raw, cP, perm,
                                      bits, top1a, featBF, featF8, proxyBF, counters);
  kegg_v10<<<512 + 2080, 512, 0, stream>>>(featBF, proxyBF, featF8, prob, bits, perm,
                                           top1a, counters, scsim, possim, S);
  kf_final_v10<<<1, 1024, 0, stream>>>(possim, scsim, S, counters, out);
}

// Round 12
// 309.393 us; speedup vs baseline: 1.3470x; 1.3470x over previous
//
#include <hip/hip_runtime.h>
#include <hip/hip_bf16.h>

#define N_ROWS 8192
#define DIM 512
#define C_CLSN 1000
#define C_PAD 1024
#define LOW_THRE (1.0f / 1000.0f)
#define LDK 40    // bf16 LDS leading dim (elems)
#define LDF8 72   // fp8 LDS leading dim (bytes): %8==0 for b64 reads, conflict-free

typedef __bf16 bf16x8 __attribute__((ext_vector_type(8)));
typedef float floatx4 __attribute__((ext_vector_type(4)));
typedef unsigned long long ull;
typedef ull ull2 __attribute__((ext_vector_type(2)));

// Scrambled class->bit bijection (consistent across ALL producers/consumers):
//   word(c) = (c>>8)*4 + (c&3)   in [0,16)
//   bit(c)  = (c>>2) & 63
// Intersection (AND of all 16 words) is invariant under this relabeling.

// ---------------- KZP: detect conf storage + stable partition ----------------
__global__ __launch_bounds__(1024) void kzp_v12(const int* __restrict__ conf,
                                                int* __restrict__ perm,
                                                int* __restrict__ counters) {
  int tid = threadIdx.x;
  __shared__ int sc[1024];
  __shared__ int sbad, sodd1, seven1, smode;
  if (tid == 0) { sbad = 0; sodd1 = 0; seven1 = 0; }
  __syncthreads();
  for (int i = tid; i < 2048; i += 1024) {
    int v = conf[i];
    if (v != 0 && v != 1) atomicOr(&sbad, 1);
    if (v == 1) { if (i & 1) atomicAdd(&sodd1, 1); else atomicAdd(&seven1, 1); }
  }
  __syncthreads();
  if (tid == 0) {
    int mode = 0;                                // int32 0/1
    if (sbad) mode = 1;                          // packed uint8 bools
    else if (seven1 > 0 && sodd1 == 0) mode = 2; // int64 0/1
    smode = mode;
  }
  __syncthreads();
  int mode = smode;
  int r0 = tid * 8;
  int f[8]; int cnt = 0;
  #pragma unroll
  for (int k = 0; k < 8; ++k) {
    int r = r0 + k;
    bool c;
    if (mode == 1)      c = ((const unsigned char*)conf)[r] != 0;
    else if (mode == 2) c = ((const long long*)conf)[r] != 0;
    else                c = conf[r] != 0;
    f[k] = c ? 1 : 0; cnt += f[k];
  }
  sc[tid] = cnt;
  __syncthreads();
  for (int off = 1; off < 1024; off <<= 1) {    // Hillis-Steele inclusive scan
    int v = (tid >= off) ? sc[tid - off] : 0;
    __syncthreads();
    sc[tid] += v;
    __syncthreads();
  }
  int incl = sc[tid];
  int excl = incl - cnt;
  int total = sc[1023];
  if (tid == 0) counters[3] = total;
  int cpos = excl;
  int npos = total + (r0 - excl);
  #pragma unroll
  for (int k = 0; k < 8; ++k) {
    if (f[k]) perm[cpos++] = r0 + k;
    else      perm[npos++] = r0 + k;
  }
}

// ---------------- KDA: prob scan (float4, parallel loads) + featnorm ---------
// wave per row; no LDS; no global atomics. cnta[p] = candidate count (nonconf).
__global__ __launch_bounds__(256) void kda_v12(const float* __restrict__ prob,
                                               const float* __restrict__ feature,
                                               const int* __restrict__ perm,
                                               const int* __restrict__ counters_ro,
                                               ull* __restrict__ bits,
                                               int* __restrict__ top1a,
                                               int* __restrict__ cnta,
                                               __bf16* __restrict__ featBF,
                                               unsigned char* __restrict__ featF8) {
  int wv = threadIdx.x >> 6, lane = threadIdx.x & 63;
  int p = blockIdx.x * 4 + wv;
  int orig = perm[p];
  bool is_conf = p < counters_ro[3];           // partitioned: conf rows first
  const float4* pr4 = (const float4*)(prob + (size_t)orig * C_CLSN);
  // 4 independent guarded float4 loads: all in flight together (1 round-trip)
  float4 v[4];
  #pragma unroll
  for (int pass = 0; pass < 4; ++pass) {
    int q = pass * 64 + lane;
    v[pass] = (q < 250) ? pr4[q] : make_float4(-1.f, -1.f, -1.f, -1.f);
  }
  float bv = -1e30f; int bidx = 0x7fffffff;
  int cnt = 0;
  ull myword = 0ULL;
  #pragma unroll
  for (int pass = 0; pass < 4; ++pass) {
    int q = pass * 64 + lane;
    bool inb = q < 250;                        // classes 4q+j < 1000 <=> q < 250
    float el[4] = {v[pass].x, v[pass].y, v[pass].z, v[pass].w};
    #pragma unroll
    for (int j = 0; j < 4; ++j) {
      float pv = el[j];
      int c = q * 4 + j;                       // per-lane sequence ascending
      if (inb && pv > bv) { bv = pv; bidx = c; }   // strict >: first max per lane
      ull m = __ballot(inb && (pv > LOW_THRE));    // word (pass*4+j), bit=lane
      cnt += (int)__popcll(m);
      if (lane == pass * 4 + j) myword = m;
    }
  }
  #pragma unroll
  for (int m = 1; m < 64; m <<= 1) {           // wave argmax, first-occurrence
    float ov = __shfl_xor(bv, m); int oi = __shfl_xor(bidx, m);
    if (ov > bv || (ov == bv && oi < bidx)) { bv = ov; bidx = oi; }
  }
  int top1 = bidx;
  if (is_conf) {                               // one-hot in scrambled mapping
    int w1 = ((top1 >> 8) << 2) | (top1 & 3);
    myword = (lane == w1) ? (1ULL << ((top1 >> 2) & 63)) : 0ULL;
  }
  if (lane < 16) bits[(size_t)p * 16 + lane] = myword;
  if (lane == 0) {
    top1a[p] = top1;
    cnta[p] = is_conf ? 0 : cnt;               // reduced in kf (no atomics)
  }
  // ---- feature normalize -> bf16 + fp8 ----
  const float* fr = feature + (size_t)orig * DIM;
  int c0 = lane * 8;
  float4 v0 = *(const float4*)(fr + c0);
  float4 v1 = *(const float4*)(fr + c0 + 4);
  float ss = v0.x*v0.x + v0.y*v0.y + v0.z*v0.z + v0.w*v0.w
           + v1.x*v1.x + v1.y*v1.y + v1.z*v1.z + v1.w*v1.w;
  #pragma unroll
  for (int m = 1; m < 64; m <<= 1) ss += __shfl_xor(ss, m);
  float scl = 1.0f / fmaxf(sqrtf(ss), 1e-12f);
  float x0 = v0.x*scl, x1 = v0.y*scl, x2 = v0.z*scl, x3 = v0.w*scl;
  float x4 = v1.x*scl, x5 = v1.y*scl, x6 = v1.z*scl, x7 = v1.w*scl;
  bf16x8 bvx;
  bvx[0] = (__bf16)x0; bvx[1] = (__bf16)x1; bvx[2] = (__bf16)x2; bvx[3] = (__bf16)x3;
  bvx[4] = (__bf16)x4; bvx[5] = (__bf16)x5; bvx[6] = (__bf16)x6; bvx[7] = (__bf16)x7;
  *(bf16x8*)(featBF + (size_t)p * DIM + c0) = bvx;
  int lo = __builtin_amdgcn_cvt_pk_fp8_f32(x0, x1, 0, false);
  lo = __builtin_amdgcn_cvt_pk_fp8_f32(x2, x3, lo, true);
  int hi = __builtin_amdgcn_cvt_pk_fp8_f32(x4, x5, 0, false);
  hi = __builtin_amdgcn_cvt_pk_fp8_f32(x6, x7, hi, true);
  int2 pk; pk.x = lo; pk.y = hi;
  *(int2*)(featF8 + (size_t)p * DIM + c0) = pk;
}

// ---------------- KBC: proxy projection + normalize -> bf16 ------------------
__global__ __launch_bounds__(256) void kbc_v12(const float* __restrict__ raw,
                                               const float* __restrict__ cP,
                                               __bf16* __restrict__ proxyBF) {
  int tid = threadIdx.x;
  int c0 = blockIdx.x * 8;
  int d0 = tid, d1 = tid + 256;
  if (c0 >= C_CLSN) {                          // zero-pad rows 1000..1023
    #pragma unroll
    for (int cc = 0; cc < 8; ++cc) {
      proxyBF[(size_t)(c0 + cc) * DIM + d0] = (__bf16)0.f;
      proxyBF[(size_t)(c0 + cc) * DIM + d1] = (__bf16)0.f;
    }
    return;
  }
  __shared__ float sraw[8 * DIM];  // 16 KB
  __shared__ float red[8 * 256];   // 8 KB
  for (int idx = tid; idx < 8 * DIM; idx += 256)
    sraw[idx] = raw[(size_t)c0 * DIM + idx];
  __syncthreads();
  float acc0[8], acc1[8];
  #pragma unroll
  for (int cc = 0; cc < 8; ++cc) { acc0[cc] = 0.f; acc1[cc] = 0.f; }
  for (int k = 0; k < DIM; k += 4) {
    float4 w0 = *(const float4*)&cP[(size_t)d0 * DIM + k];
    float4 w1 = *(const float4*)&cP[(size_t)d1 * DIM + k];
    #pragma unroll
    for (int cc = 0; cc < 8; ++cc) {
      const float* sr = &sraw[cc * DIM + k];
      acc0[cc] += sr[0]*w0.x + sr[1]*w0.y + sr[2]*w0.z + sr[3]*w0.w;
      acc1[cc] += sr[0]*w1.x + sr[1]*w1.y + sr[2]*w1.z + sr[3]*w1.w;
    }
  }
  #pragma unroll
  for (int cc = 0; cc < 8; ++cc)
    red[cc * 256 + tid] = acc0[cc]*acc0[cc] + acc1[cc]*acc1[cc];
  __syncthreads();
  for (int s = 128; s > 0; s >>= 1) {
    if (tid < s)
      #pragma unroll
      for (int cc = 0; cc < 8; ++cc)
        red[cc * 256 + tid] += red[cc * 256 + tid + s];
    __syncthreads();
  }
  #pragma unroll
  for (int cc = 0; cc < 8; ++cc) {
    float scl = 1.0f / fmaxf(sqrtf(red[cc * 256]), 1e-12f);
    proxyBF[(size_t)(c0 + cc) * DIM + d0] = (__bf16)(acc0[cc] * scl);
    proxyBF[(size_t)(c0 + cc) * DIM + d1] = (__bf16)(acc1[cc] * scl);
  }
}

// ---------------- KEGG: grid-partitioned fusion ------------------------------
// blocks [0,512): kg  P=feat@proxy^T (bf16) + pos-pair epilogue
// blocks [512,2592): ke  fp8 sim GEMM + mask + sum(exp)
__global__ __launch_bounds__(512) void kegg_v12(const __bf16* __restrict__ featBF,
                                                const __bf16* __restrict__ proxyBF,
                                                const unsigned char* __restrict__ featF8,
                                                const float* __restrict__ prob,
                                                const ull* __restrict__ bits,
                                                const int* __restrict__ perm,
                                                const int* __restrict__ top1a,
                                                const int* __restrict__ counters_ro,
                                                float* __restrict__ scsim,
                                                float* __restrict__ possim,
                                                float* __restrict__ S) {
  __shared__ __align__(16) char smem[35840];
  int tid = threadIdx.x;
  int wv = tid >> 6, lane = tid & 63;
  int wi = wv >> 2, wj = wv & 3;            // 2x4 wave grid: 64 rows x 32 cols
  int lr = lane >> 4, lc = lane & 15;

  floatx4 acc[4][2];
  floatx4 zero = {0.f, 0.f, 0.f, 0.f};
  #pragma unroll
  for (int ti = 0; ti < 4; ++ti)
    #pragma unroll
    for (int tj = 0; tj < 2; ++tj) acc[ti][tj] = zero;

  if (blockIdx.x < 512) {
    // ================= KG path (bf16) =================
    __bf16* As = (__bf16*)smem;                  // 10240 B
    __bf16* Bs = (__bf16*)(smem + 10240);        // 10240 B
    int* pO  = (int*)(smem + 20480);             // 512 B
    int* t1r = (int*)(smem + 20992);             // 512 B
    int bi = blockIdx.x >> 3;     // 64 row-tiles
    int bj = blockIdx.x & 7;      // 8 class-tiles
    if (tid < 128) { pO[tid] = perm[bi * 128 + tid]; t1r[tid] = top1a[bi * 128 + tid]; }
    const __bf16* Abase = featBF + (size_t)bi * 128 * DIM;
    const __bf16* Bbase = proxyBF + (size_t)bj * 128 * DIM;
    for (int kt = 0; kt < DIM; kt += 32) {
      __syncthreads();
      {
        int rw = tid >> 2, cc = (tid & 3) * 8;
        *(bf16x8*)&As[rw * LDK + cc] = *(const bf16x8*)&Abase[(size_t)rw * DIM + kt + cc];
        *(bf16x8*)&Bs[rw * LDK + cc] = *(const bf16x8*)&Bbase[(size_t)rw * DIM + kt + cc];
      }
      __syncthreads();
      bf16x8 afr[4], bfr[2];
      #pragma unroll
      for (int ti = 0; ti < 4; ++ti)
        afr[ti] = *(bf16x8*)&As[(wi * 64 + ti * 16 + lc) * LDK + lr * 8];
      #pragma unroll
      for (int tj = 0; tj < 2; ++tj)
        bfr[tj] = *(bf16x8*)&Bs[(wj * 32 + tj * 16 + lc) * LDK + lr * 8];
      #pragma unroll
      for (int ti = 0; ti < 4; ++ti)
        #pragma unroll
        for (int tj = 0; tj < 2; ++tj)
          acc[ti][tj] = __builtin_amdgcn_mfma_f32_16x16x32_bf16(afr[ti], bfr[tj], acc[ti][tj], 0, 0, 0);
    }
    __syncthreads();
    #pragma unroll
    for (int ti = 0; ti < 4; ++ti) {
      int ibase = wi * 64 + ti * 16 + lr * 4;   // C/D: row=(lane>>4)*4+reg, col=lane&15
      float rs[4] = {0.f, 0.f, 0.f, 0.f};
      #pragma unroll
      for (int rr = 0; rr < 4; ++rr) {
        int il = ibase + rr;
        int orig = pO[il];
        int t1 = t1r[il];
        const float* prow = prob + (size_t)orig * C_CLSN;
        #pragma unroll
        for (int tj = 0; tj < 2; ++tj) {
          int c = bj * 128 + wj * 32 + tj * 16 + lc;
          float P = acc[ti][tj][rr];
          float pv = (c < C_CLSN) ? prow[c] : 0.f;
          if (pv > LOW_THRE) rs[rr] += pv * P;
          if (c == t1) possim[bi * 128 + il] = P;   // single writer grid-wide
        }
      }
      #pragma unroll
      for (int m = 1; m < 16; m <<= 1)
        #pragma unroll
        for (int rr = 0; rr < 4; ++rr) rs[rr] += __shfl_xor(rs[rr], m);
      if (lc == 0) {
        #pragma unroll
        for (int rr = 0; rr < 4; ++rr)
          atomicAdd(&scsim[bi * 128 + ibase + rr], rs[rr]);
      }
    }
    return;
  }

  // ================= KE path (fp8) =================
  unsigned char* As = (unsigned char*)smem;           // 9216 B
  unsigned char* Bs = (unsigned char*)(smem + 9216);  // 9216 B
  ull* bsJ = (ull*)smem;                              // 16384 B, aliases As+Bs post-loop
  ull* bsI = (ull*)(smem + 18432);                    // 16384 B (dedicated)
  int* t1I = (int*)(smem + 34816);                    // 512 B
  int* t1J = (int*)(smem + 35328);                    // 512 B

  // LCG swizzle interleaves heavy (mode-3) and light tiles
  int b = (int)(((long long)(blockIdx.x - 512) * 997) % 2080);
  int bi = 0, rem = b;
  while (rem >= 64 - bi) { rem -= 64 - bi; bi++; }
  int bj = bi + rem;

  int nconf = counters_ro[3];
  bool allcI = (bi * 128 + 128) <= nconf;
  bool allcJ = (bj * 128 + 128) <= nconf;
  int mode = allcJ ? 0 : (allcI ? 1 : 3);   // bi<=bj + conf-first => allcJ -> allcI

  if (tid < 128)      t1I[tid]       = top1a[bi * 128 + tid];
  else if (tid < 256) t1J[tid - 128] = top1a[bj * 128 + tid - 128];
  if (mode == 3) {    // bsI dedicated: stage before K-loop
    #pragma unroll
    for (int e = 0; e < 4; ++e) {
      int flat = tid + e * 512;
      int row = flat & 127, w = flat >> 7;
      bsI[w * 128 + row] = bits[(size_t)(bi * 128 + row) * 16 + w];
    }
  }

  int rw = tid >> 2, cc = (tid & 3) * 16;
  const unsigned char* Aptr = featF8 + (size_t)(bi * 128 + rw) * DIM + cc;
  const unsigned char* Bptr = featF8 + (size_t)(bj * 128 + rw) * DIM + cc;
  int4 pa = *(const int4*)Aptr;             // prefetch kt=0
  int4 pb = *(const int4*)Bptr;

  for (int kt = 0; kt < DIM; kt += 64) {    // 8 iterations
    __syncthreads();
    *(int4*)&As[rw * LDF8 + cc] = pa;
    *(int4*)&Bs[rw * LDF8 + cc] = pb;
    __syncthreads();
    if (kt + 64 < DIM) {                    // prefetch next iter during MFMA
      pa = *(const int4*)(Aptr + kt + 64);
      pb = *(const int4*)(Bptr + kt + 64);
    }
    // fp8 16x16x32 frag: row = lane&15, k = (lane>>4)*8 + byte
    #pragma unroll
    for (int ks = 0; ks < 2; ++ks) {
      long a_[4], b_[2];
      #pragma unroll
      for (int ti = 0; ti < 4; ++ti)
        a_[ti] = *(const long*)&As[(wi * 64 + ti * 16 + lc) * LDF8 + ks * 32 + lr * 8];
      #pragma unroll
      for (int tj = 0; tj < 2; ++tj)
        b_[tj] = *(const long*)&Bs[(wj * 32 + tj * 16 + lc) * LDF8 + ks * 32 + lr * 8];
      #pragma unroll
      for (int ti = 0; ti < 4; ++ti)
        #pragma unroll
        for (int tj = 0; tj < 2; ++tj)
          acc[ti][tj] = __builtin_amdgcn_mfma_f32_16x16x32_fp8_fp8(a_[ti], b_[tj], acc[ti][tj], 0, 0, 0);
    }
  }
  __syncthreads();              // all waves done reading As/Bs
  if (mode != 0) {              // stage bsJ into the aliased region
    #pragma unroll
    for (int e = 0; e < 4; ++e) {
      int flat = tid + e * 512;
      int row = flat & 127, w = flat >> 7;
      bsJ[w * 128 + row] = bits[(size_t)(bj * 128 + row) * 16 + w];
    }
  }
  __syncthreads();

  int tJv[2];
  #pragma unroll
  for (int tj = 0; tj < 2; ++tj) tJv[tj] = t1J[wj * 32 + tj * 16 + lc];

  float cs[2] = {0.f, 0.f};     // mirror column partial sums
  #pragma unroll
  for (int ti = 0; ti < 4; ++ti) {
    int ibase = wi * 64 + ti * 16 + lr * 4;
    unsigned inter[8];
    if (mode == 0) {            // conf x conf: intersect <=> same top1
      #pragma unroll
      for (int rr = 0; rr < 4; ++rr) {
        int tI = t1I[ibase + rr];
        #pragma unroll
        for (int tj = 0; tj < 2; ++tj) inter[rr * 2 + tj] = (tI == tJv[tj]);
      }
    } else if (mode == 1) {     // conf-I: probe J's bitset (scrambled mapping)
      #pragma unroll
      for (int rr = 0; rr < 4; ++rr) {
        int tI = t1I[ibase + rr];
        int w = ((tI >> 8) << 2) | (tI & 3);
        int bb = (tI >> 2) & 63;
        #pragma unroll
        for (int tj = 0; tj < 2; ++tj) {
          ull word = bsJ[w * 128 + wj * 32 + tj * 16 + lc];
          inter[rr * 2 + tj] = (unsigned)((word >> bb) & 1ULL);
        }
      }
    } else {                    // general: full 1024-bit AND (mapping-agnostic)
      #pragma unroll
      for (int q = 0; q < 8; ++q) inter[q] = 0u;
      #pragma unroll
      for (int w = 0; w < 16; ++w) {
        ull2 a01 = *(const ull2*)&bsI[w * 128 + ibase];
        ull2 a23 = *(const ull2*)&bsI[w * 128 + ibase + 2];
        ull aw[4] = {a01[0], a01[1], a23[0], a23[1]};
        ull bw[2];
        #pragma unroll
        for (int tj = 0; tj < 2; ++tj) bw[tj] = bsJ[w * 128 + wj * 32 + tj * 16 + lc];
        #pragma unroll
        for (int rr = 0; rr < 4; ++rr)
          #pragma unroll
          for (int tj = 0; tj < 2; ++tj) {
            ull t = aw[rr] & bw[tj];
            inter[rr * 2 + tj] |= (unsigned)(t | (t >> 32));
          }
      }
    }
    float rs[4] = {0.f, 0.f, 0.f, 0.f};
    #pragma unroll
    for (int rr = 0; rr < 4; ++rr)
      #pragma unroll
      for (int tj = 0; tj < 2; ++tj) {
        float sim = acc[ti][tj][rr];
        sim = fminf(sim, 1.0f);   // unit rows: math no-op
        float e_ = ((inter[rr * 2 + tj] == 0u) && (sim >= 1e-6f)) ? __expf(sim) : 0.f;
        rs[rr] += e_;
        cs[tj] += e_;
      }
    #pragma unroll
    for (int m = 1; m < 16; m <<= 1)
      #pragma unroll
      for (int rr = 0; rr < 4; ++rr) rs[rr] += __shfl_xor(rs[rr], m);
    if (lc == 0) {
      #pragma unroll
      for (int rr = 0; rr < 4; ++rr)
        atomicAdd(&S[(size_t)bi * 128 + ibase + rr], rs[rr]);
    }
  }
  if (bi != bj) {   // mirror: (j,i) identical by symmetry -> column sums
    #pragma unroll
    for (int tj = 0; tj < 2; ++tj) {
      cs[tj] += __shfl_xor(cs[tj], 16);   // reduce over lr
      cs[tj] += __shfl_xor(cs[tj], 32);
    }
    if (lr == 0) {
      #pragma unroll
      for (int tj = 0; tj < 2; ++tj)
        atomicAdd(&S[(size_t)bj * 128 + wj * 32 + tj * 16 + lc], cs[tj]);
    }
  }
}

// ---------------- KF: final reduction (loss + sc_num) — fp32 out -------------
// NOTE r11 bug: cnta/counters were swapped at the CALL SITE. Argument order
// here matches the launch exactly: (possim, scsim, S, cnta, counters, out).
__global__ __launch_bounds__(1024) void kf_final_v12(const float* __restrict__ possim,
                                                     const float* __restrict__ scsim,
                                                     const float* __restrict__ S,
                                                     const int* __restrict__ cnta,
                                                     const int* __restrict__ counters,
                                                     float* __restrict__ out) {
  __shared__ float red[1024];
  __shared__ int redi[1024];
  int tid = threadIdx.x;
  int nconf = counters[3];
  float local = 0.f;
  int lcnt = 0;
  for (int i = tid; i < N_ROWS; i += 1024) {
    float p = (i < nconf) ? possim[i] : scsim[i];
    p = fminf(fmaxf(p, -1.1f), 1.1f);      // |pos|<=1 math bound (safety)
    float s = fmaxf(S[i], 0.0f);
    local += logf(expf(p) + s) - p;        // -logp[:,0]
    lcnt += cnta[i];
  }
  red[tid] = local;
  redi[tid] = lcnt;
  __syncthreads();
  for (int s = 512; s > 0; s >>= 1) {
    if (tid < s) { red[tid] += red[tid + s]; redi[tid] += redi[tid + s]; }
    __syncthreads();
  }
  if (tid == 0) {
    float loss = red[0] / (float)N_ROWS;
    int denom = N_ROWS - nconf;            // exact: count of non-conf rows
    int scc = redi[0];
    float scn = (denom > 0) ? ((float)scc / (float)denom) : 0.f;
    out[0] = loss;
    out[1] = scn;
  }
}

extern "C" void kernel_launch(void* const* d_in, const int* in_sizes, int n_in,
                              void* d_out, int out_size, void* d_ws, size_t ws_size,
                              hipStream_t stream) {
  const float* feature   = (const float*)d_in[0];
  const float* proxy_raw = (const float*)d_in[1];
  const float* cP        = (const float*)d_in[2];
  const float* prob      = (const float*)d_in[3];
  const int*   conf      = (const int*)d_in[4];
  float* out = (float*)d_out;

  size_t need = (size_t)N_ROWS * DIM * 2      // featBF    8 MB
              + (size_t)N_ROWS * DIM          // featF8    4 MB
              + (size_t)C_PAD * DIM * 2       // proxyBF   1 MB
              + (size_t)N_ROWS * 16 * 8       // bits      1 MB
              + (size_t)N_ROWS * 4            // possim
              + (size_t)N_ROWS * 4            // S
              + (size_t)N_ROWS * 4            // scsim
              + 256                           // counters
              + (size_t)N_ROWS * 4            // perm
              + (size_t)N_ROWS * 4            // top1a
              + (size_t)N_ROWS * 4;           // cnta
  if (ws_size < need) return;

  char* ws = (char*)d_ws;
  __bf16* featBF  = (__bf16*)ws;              ws += (size_t)N_ROWS * DIM * 2;
  unsigned char* featF8 = (unsigned char*)ws; ws += (size_t)N_ROWS * DIM;
  __bf16* proxyBF = (__bf16*)ws;              ws += (size_t)C_PAD * DIM * 2;
  ull* bits       = (ull*)ws;                 ws += (size_t)N_ROWS * 16 * 8;
  float* possim   = (float*)ws;               ws += (size_t)N_ROWS * 4;
  float* S        = (float*)ws;               ws += (size_t)N_ROWS * 4;  // S,scsim,counters contiguous
  float* scsim    = (float*)ws;               ws += (size_t)N_ROWS * 4;
  int* counters   = (int*)ws;                 ws += 256;  // [3]=nconf
  int* perm       = (int*)ws;                 ws += (size_t)N_ROWS * 4;
  int* top1a      = (int*)ws;                 ws += (size_t)N_ROWS * 4;
  int* cnta       = (int*)ws;                 ws += (size_t)N_ROWS * 4;

  hipMemsetAsync(S, 0, (size_t)N_ROWS * 8 + 256, stream);  // zero S + scsim + counters
  kzp_v12<<<1, 1024, 0, stream>>>(conf, perm, counters);
  kda_v12<<<N_ROWS / 4, 256, 0, stream>>>(prob, feature, perm, counters,
                                          bits, top1a, cnta, featBF, featF8);
  kbc_v12<<<C_PAD / 8, 256, 0, stream>>>(proxy_raw, cP, proxyBF);
  kegg_v12<<<512 + 2080, 512, 0, stream>>>(featBF, proxyBF, featF8, prob, bits, perm,
                                           top1a, counters, scsim, possim, S);
  kf_final_v12<<<1, 1024, 0, stream>>>(possim, scsim, S, cnta, counters, out);
}